// Round 12
// baseline (265.495 us; speedup 1.0000x reference)
//
#include <hip/hip_runtime.h>
#include <hip/hip_fp16.h>

#define DIMC 768
#define NH 4
#define HD 192
#define SEQ 2048
#define NBATCH 8
#define SCALE_F 0.07216878364870323f  /* 192^-0.5 */
#define LOG2E   1.4426950408889634f
#define DEFER_THR 8.0f                /* log2-domain defer-max threshold */

typedef _Float16 f16x8 __attribute__((ext_vector_type(8)));
typedef _Float16 f16x4 __attribute__((ext_vector_type(4)));
typedef float    f32x4 __attribute__((ext_vector_type(4)));

__device__ __forceinline__ f32x4 mfma16(f16x8 a, f16x8 b, f32x4 c) {
    return __builtin_amdgcn_mfma_f32_16x16x32_f16(a, b, c, 0, 0, 0);
}
__device__ __forceinline__ void gl16(const void* g, void* l) {
    __builtin_amdgcn_global_load_lds(
        (const __attribute__((address_space(1))) unsigned int*)g,
        (__attribute__((address_space(3))) unsigned int*)l, 16, 0, 0);
}
__device__ __forceinline__ float exp2_hw(float x) {
    return __builtin_amdgcn_exp2f(x);
}

// ---------------------------------------------------------------------------
// cvt_w: fp32 W[768][768] -> fp16 pre-swizzled 192-row tile images.
// idx = ((nt*12 + t)*192 + rr)*64 + (cc ^ ((rr&7)<<3)).
// ---------------------------------------------------------------------------
__global__ __launch_bounds__(256)
void cvt_w(const float* __restrict__ w0, const float* __restrict__ w1,
           const float* __restrict__ w2, const float* __restrict__ w3,
           _Float16* __restrict__ o0, _Float16* __restrict__ o1,
           _Float16* __restrict__ o2, _Float16* __restrict__ o3)
{
    const float* src = (blockIdx.y == 0) ? w0 : (blockIdx.y == 1) ? w1
                     : (blockIdx.y == 2) ? w2 : w3;
    _Float16* dst = (blockIdx.y == 0) ? o0 : (blockIdx.y == 1) ? o1
                  : (blockIdx.y == 2) ? o2 : o3;
    const int e   = blockIdx.x * 256 + threadIdx.x;
    const int row = e / 192;
    const int col = (e - row * 192) * 4;
    const float4 v = *(const float4*)(src + (size_t)row * DIMC + col);
    const int nt = row / 192, rr = row - nt * 192;
    const int t  = col >> 6,  cc = col & 63;
    f16x4 h = {(_Float16)v.x, (_Float16)v.y, (_Float16)v.z, (_Float16)v.w};
    *(f16x4*)(dst + ((size_t)(nt * 12 + t) * 192 + rr) * 64 + (cc ^ ((rr & 7) << 3))) = h;
}

// ---------------------------------------------------------------------------
// 8-phase 256x192 GEMM helpers: 8 waves (2M x 4N), wave tile 128x48 (NF=3).
// ---------------------------------------------------------------------------
__device__ __forceinline__ void phase_reads(const _Float16* As, const _Float16* Bs,
                                            int wr, int wc, int l15, int l4, int q,
                                            f16x8 af[2][2], f16x8 bf[2][3], bool loadB)
{
    #pragma unroll
    for (int ks = 0; ks < 2; ++ks) {
        const int cb = ks * 32 + l4 * 8;
        #pragma unroll
        for (int mm = 0; mm < 2; ++mm) {
            const int row = wr * 128 + (q * 2 + mm) * 16 + l15;
            af[ks][mm] = *(const f16x8*)(As + (size_t)row * 64 + (cb ^ ((row & 7) << 3)));
        }
        if (loadB) {
            #pragma unroll
            for (int n = 0; n < 3; ++n) {
                const int row = wc * 48 + n * 16 + l15;
                bf[ks][n] = *(const f16x8*)(Bs + (size_t)row * 64 + (cb ^ ((row & 7) << 3)));
            }
        }
    }
}
__device__ __forceinline__ void phase_mfma(int q, f16x8 af[2][2], f16x8 bf[2][3],
                                           f32x4 acc[8][3])
{
    __builtin_amdgcn_s_barrier();
    asm volatile("s_waitcnt lgkmcnt(0)" ::: "memory");
    __builtin_amdgcn_s_setprio(1);
    #pragma unroll
    for (int ks = 0; ks < 2; ++ks)
        #pragma unroll
        for (int mm = 0; mm < 2; ++mm)
            #pragma unroll
            for (int n = 0; n < 3; ++n)
                acc[q * 2 + mm][n] = mfma16(af[ks][mm], bf[ks][n], acc[q * 2 + mm][n]);
    __builtin_amdgcn_s_setprio(0);
}

// ---------------------------------------------------------------------------
// Projection GEMM (8-phase, 256x192, grid 64x4 = 256 = 1/CU). Verbatim r11.
// ---------------------------------------------------------------------------
template<int MODE>
__global__ __launch_bounds__(512, 2)
void gemm_p8(const float* __restrict__ A, const _Float16* __restrict__ Wimg,
             _Float16* __restrict__ Y, float scale)
{
    __shared__ __attribute__((aligned(16))) _Float16 Abuf[2][16384];
    __shared__ __attribute__((aligned(16))) _Float16 Bbuf[2][12288];

    const int tid  = threadIdx.x;
    const int wid  = tid >> 6;
    const int lane = tid & 63;
    const int l15  = lane & 15;
    const int l4   = lane >> 4;
    const int wr   = wid >> 2;
    const int wc   = wid & 3;
    const int m0   = blockIdx.x * 256;
    const int nt   = blockIdx.y;

    const unsigned char* Wt = (const unsigned char*)(Wimg + (size_t)nt * 12 * 12288);

    f32x4 acc[8][3];
    #pragma unroll
    for (int m = 0; m < 8; ++m)
        #pragma unroll
        for (int n = 0; n < 3; ++n)
            acc[m][n] = (f32x4){0.f, 0.f, 0.f, 0.f};

    float4 rA[8];
    auto loadA = [&](int t) {
        #pragma unroll
        for (int p = 0; p < 8; ++p) {
            const int linear = p * 512 + tid;
            const int row = linear >> 4, qc = (linear & 15) * 4;
            rA[p] = *(const float4*)(A + (size_t)(m0 + row) * DIMC + t * 64 + qc);
        }
    };
    auto writeA = [&](int buf) {
        #pragma unroll
        for (int p = 0; p < 8; ++p) {
            const int linear = p * 512 + tid;
            const int row = linear >> 4, qc = (linear & 15) * 4;
            f16x4 h = {(_Float16)rA[p].x, (_Float16)rA[p].y,
                       (_Float16)rA[p].z, (_Float16)rA[p].w};
            *(f16x4*)(&Abuf[buf][row * 64 + (qc ^ ((row & 7) << 3))]) = h;
        }
    };
    auto stageB = [&](int t) {
        const unsigned char* src = Wt + (size_t)t * 24576;
        #pragma unroll
        for (int u = 0; u < 3; ++u)
            gl16(src + u * 8192 + tid * 16, &Bbuf[t & 1][u * 4096 + tid * 8]);
    };

    loadA(0);
    stageB(0);
    asm volatile("s_waitcnt vmcnt(3)" ::: "memory");
    writeA(0);
    loadA(1);
    asm volatile("s_waitcnt vmcnt(8)" ::: "memory");
    asm volatile("s_waitcnt lgkmcnt(0)" ::: "memory");
    __builtin_amdgcn_s_barrier();

    for (int t = 0; t < 12; ++t) {
        const _Float16* As = &Abuf[t & 1][0];
        const _Float16* Bs = &Bbuf[t & 1][0];
        f16x8 af[2][2], bf[2][3];

        phase_reads(As, Bs, wr, wc, l15, l4, 0, af, bf, true);
        if (t < 11) stageB(t + 1);
        phase_mfma(0, af, bf, acc);
        __builtin_amdgcn_s_barrier();

        phase_reads(As, Bs, wr, wc, l15, l4, 1, af, bf, false);
        phase_mfma(1, af, bf, acc);
        __builtin_amdgcn_s_barrier();

        phase_reads(As, Bs, wr, wc, l15, l4, 2, af, bf, false);
        if (t < 11) {
            asm volatile("s_waitcnt vmcnt(3)" ::: "memory");
            writeA((t + 1) & 1);
            if (t < 10) loadA(t + 2);
        }
        phase_mfma(2, af, bf, acc);
        __builtin_amdgcn_s_barrier();

        phase_reads(As, Bs, wr, wc, l15, l4, 3, af, bf, false);
        phase_mfma(3, af, bf, acc);
        if (t < 10)       asm volatile("s_waitcnt vmcnt(8)" ::: "memory");
        else if (t == 10) asm volatile("s_waitcnt vmcnt(0)" ::: "memory");
        __builtin_amdgcn_s_barrier();
    }

    #pragma unroll
    for (int m = 0; m < 8; ++m) {
        const int rbase = m0 + wr * 128 + m * 16 + l4 * 4;
        #pragma unroll
        for (int n = 0; n < 3; ++n) {
            const int d = wc * 48 + n * 16 + l15;
            #pragma unroll
            for (int j = 0; j < 4; ++j) {
                const int r  = rbase + j;
                const int b  = r >> 11;
                const int nn = r & (SEQ - 1);
                if (MODE == 0) {
                    Y[((size_t)(b * NH + nt) * SEQ + nn) * HD + d] =
                        (_Float16)(acc[m][n][j] * scale);
                } else {
                    const int kt  = nn >> 5;
                    const int key = nn & 31;
                    const size_t tb = ((size_t)(b * NH + nt) * 64 + kt) * 12288;
                    size_t idx;
                    if (MODE == 1)
                        idx = tb + (size_t)key * HD + (d ^ ((key & 7) << 3));
                    else
                        idx = tb + 6144 + (((size_t)(key >> 3) * 192 + d) << 3) + (key & 7);
                    Y[idx] = (_Float16)acc[m][n][j];
                }
            }
        }
    }
}

// ---------------------------------------------------------------------------
// Final GEMM (8-phase, 256x192, grid 64x4). Verbatim r11.
// ---------------------------------------------------------------------------
__global__ __launch_bounds__(512, 2)
void gemm_x8(const _Float16* __restrict__ Ximg, const _Float16* __restrict__ Wimg,
             float* __restrict__ out, const float* __restrict__ bias)
{
    __shared__ __attribute__((aligned(16))) _Float16 Abuf[2][16384];
    __shared__ __attribute__((aligned(16))) _Float16 Bbuf[2][12288];

    const int tid  = threadIdx.x;
    const int wid  = tid >> 6;
    const int lane = tid & 63;
    const int l15  = lane & 15;
    const int l4   = lane >> 4;
    const int wr   = wid >> 2;
    const int wc   = wid & 3;
    const int mt   = blockIdx.x;
    const int nt   = blockIdx.y;

    const unsigned char* Xt = (const unsigned char*)(Ximg + (size_t)mt * 12 * 16384);
    const unsigned char* Wt = (const unsigned char*)(Wimg + (size_t)nt * 12 * 12288);

    f32x4 acc[8][3];
    #pragma unroll
    for (int m = 0; m < 8; ++m)
        #pragma unroll
        for (int n = 0; n < 3; ++n)
            acc[m][n] = (f32x4){0.f, 0.f, 0.f, 0.f};

    auto stageAB = [&](int t) {
        const unsigned char* sa = Xt + (size_t)t * 32768;
        const unsigned char* sb = Wt + (size_t)t * 24576;
        #pragma unroll
        for (int u = 0; u < 4; ++u)
            gl16(sa + u * 8192 + tid * 16, &Abuf[t & 1][u * 4096 + tid * 8]);
        #pragma unroll
        for (int u = 0; u < 3; ++u)
            gl16(sb + u * 8192 + tid * 16, &Bbuf[t & 1][u * 4096 + tid * 8]);
    };

    stageAB(0);
    asm volatile("s_waitcnt vmcnt(0)" ::: "memory");
    __builtin_amdgcn_s_barrier();

    for (int t = 0; t < 12; ++t) {
        const _Float16* As = &Abuf[t & 1][0];
        const _Float16* Bs = &Bbuf[t & 1][0];
        f16x8 af[2][2], bf[2][3];

        phase_reads(As, Bs, wr, wc, l15, l4, 0, af, bf, true);
        if (t < 11) stageAB(t + 1);
        phase_mfma(0, af, bf, acc);
        __builtin_amdgcn_s_barrier();

        phase_reads(As, Bs, wr, wc, l15, l4, 1, af, bf, false);
        phase_mfma(1, af, bf, acc);
        __builtin_amdgcn_s_barrier();

        phase_reads(As, Bs, wr, wc, l15, l4, 2, af, bf, false);
        phase_mfma(2, af, bf, acc);
        __builtin_amdgcn_s_barrier();

        phase_reads(As, Bs, wr, wc, l15, l4, 3, af, bf, false);
        phase_mfma(3, af, bf, acc);
        if (t < 11) asm volatile("s_waitcnt vmcnt(0)" ::: "memory");
        __builtin_amdgcn_s_barrier();
    }

    #pragma unroll
    for (int m = 0; m < 8; ++m) {
        const int rbase = mt * 256 + wr * 128 + m * 16 + l4 * 4;
        #pragma unroll
        for (int n = 0; n < 3; ++n) {
            const int c = nt * 192 + wc * 48 + n * 16 + l15;
            const float bv = bias[c];
            #pragma unroll
            for (int j = 0; j < 4; ++j)
                out[(size_t)(rbase + j) * DIMC + c] = acc[m][n][j] + bv;
        }
    }
}

// ---------------------------------------------------------------------------
// Flash attention, cross-tile pipelined (T15 at viable VGPR):
// per iter: {vmcnt(0), barrier, stage[K(t+2)|V(t+1) by wave role],
//            QK^T(t+1) MFMA ∥ softmax(t) VALU, Ps, PV(t)}.
// K 3-deep / V 2-deep rotating pointers; ONE barrier per tile; 70KB LDS,
// 2 blocks/CU. pA/pB static via 2x unroll.
// ---------------------------------------------------------------------------
__global__ __launch_bounds__(512, 4)
void attn9(const _Float16* __restrict__ Qh, const _Float16* __restrict__ KVimg,
           _Float16* __restrict__ Ximg)
{
    __shared__ __attribute__((aligned(16))) _Float16 KB[3][6144];
    __shared__ __attribute__((aligned(16))) _Float16 VB[2][6144];
    __shared__ __attribute__((aligned(16))) _Float16 Ps[8][16][40];

    const int tid  = threadIdx.x;
    const int wid  = tid >> 6;
    const int lane = tid & 63;
    const int l15  = lane & 15;
    const int l4   = lane >> 4;

    const int bid   = blockIdx.x;
    const int local = bid >> 3;
    const int bh    = (bid & 7) * 4 + (local >> 4);
    const int qt    = local & 15;

    const unsigned char* KVt = (const unsigned char*)KVimg + (size_t)bh * 64 * 24576;

    // staging roles: wid<4 -> K tile (12KB, 3 gl16 over tid 0..255),
    //                wid>=4 -> V tile (12KB, 3 gl16 over tid-256).
    auto stageK = [&](_Float16* dst, int t) {
        const unsigned char* src = KVt + (size_t)t * 24576;
        #pragma unroll
        for (int s = 0; s < 3; ++s)
            gl16(src + (size_t)(s * 256 + tid) * 16, dst + (size_t)(s * 256 + tid) * 8);
    };
    auto stageV = [&](_Float16* dst, int t) {
        const int i = tid - 256;
        const unsigned char* src = KVt + (size_t)t * 24576 + 12288;
        #pragma unroll
        for (int s = 0; s < 3; ++s)
            gl16(src + (size_t)(s * 256 + i) * 16, dst + (size_t)(s * 256 + i) * 8);
    };

    // Q fragments (scale*log2e pre-folded)
    const int q0 = qt * 128 + wid * 16;
    const size_t qbase = (size_t)bh * SEQ * HD;
    f16x8 qf[6];
    #pragma unroll
    for (int kk = 0; kk < 6; ++kk)
        qf[kk] = *(const f16x8*)(Qh + qbase + (size_t)(q0 + l15) * HD + kk * 32 + l4 * 8);
    __builtin_amdgcn_sched_barrier(0);   // pin Q loads before stage loads

    // prologue stages: K-waves issue K0,K1 (6 loads); V-waves issue V0 (3)
    if (wid < 4) { stageK(&KB[0][0], 0); stageK(&KB[1][0], 1); }
    else         { stageV(&VB[0][0], 0); }

    f32x4 Oacc[12];
    #pragma unroll
    for (int nd = 0; nd < 12; ++nd)
        Oacc[nd] = (f32x4){0.f, 0.f, 0.f, 0.f};
    float mrow[4], lrow[4];
    #pragma unroll
    for (int j = 0; j < 4; ++j) { mrow[j] = -1e30f; lrow[j] = 0.f; }

    const _Float16* kRead  = &KB[1][0];   // K(t+1) during iter t
    _Float16*       kStage = &KB[2][0];   // K(t+2) target
    _Float16*       kDead  = &KB[0][0];   // free after qkt(t)
    const _Float16* vRead  = &VB[0][0];
    _Float16*       vStage = &VB[1][0];

    auto qkt = [&](const _Float16* Kc, f32x4 (&p)[2]) {
        p[0] = (f32x4){0.f, 0.f, 0.f, 0.f};
        p[1] = (f32x4){0.f, 0.f, 0.f, 0.f};
        #pragma unroll
        for (int kk = 0; kk < 6; ++kk) {
            const int cb = (kk * 32 + l4 * 8) ^ ((l15 & 7) << 3);
            #pragma unroll
            for (int nn = 0; nn < 2; ++nn) {
                const f16x8 kf = *(const f16x8*)(Kc + (size_t)(nn * 16 + l15) * HD + cb);
                p[nn] = mfma16(qf[kk], kf, p[nn]);
            }
        }
    };

    // prologue gate: own Q(6) + first K tile (K-waves) landed
    asm volatile("s_waitcnt vmcnt(3)" ::: "memory");
    __builtin_amdgcn_s_barrier();
    __builtin_amdgcn_sched_barrier(0);

    f32x4 pA[2], pB[2];
    qkt(&KB[0][0], pA);   // QK^T(0)

    auto body = [&](int t, f32x4 (&pCur)[2], f32x4 (&pNxt)[2]) {
        asm volatile("s_waitcnt vmcnt(0)" ::: "memory");   // loads issued last iter
        __builtin_amdgcn_s_barrier();
        __builtin_amdgcn_sched_barrier(0);

        // stage next tiles (safe: all waves past PV(t-1))
        if (wid < 4) { if (t + 2 < 64) stageK(kStage, t + 2); }
        else         { if (t + 1 < 64) stageV(vStage, t + 1); }

        __builtin_amdgcn_s_setprio(1);
        // ---- QK^T(t+1) (MFMA) — independent of softmax(t) below ----
        if (t + 1 < 64) qkt(kRead, pNxt);

        // ---- softmax(t) on pCur (VALU; interleaves into MFMA shadow) ----
        float lm[4];
        bool need = false;
        #pragma unroll
        for (int j = 0; j < 4; ++j) {
            lm[j] = fmaxf(pCur[0][j], pCur[1][j]);
            need |= (lm[j] > mrow[j] + DEFER_THR);
        }
        if (__any(need)) {
            #pragma unroll
            for (int j = 0; j < 4; ++j) {
                float v = lm[j];
                v = fmaxf(v, __shfl_xor(v, 1));
                v = fmaxf(v, __shfl_xor(v, 2));
                v = fmaxf(v, __shfl_xor(v, 4));
                v = fmaxf(v, __shfl_xor(v, 8));
                const float mnew = fmaxf(mrow[j], v);
                const float f    = exp2_hw(mrow[j] - mnew);
                mrow[j] = mnew;
                lrow[j] *= f;
                #pragma unroll
                for (int nd = 0; nd < 12; ++nd)
                    Oacc[nd][j] *= f;
            }
        }
        #pragma unroll
        for (int j = 0; j < 4; ++j) {
            const float p0 = exp2_hw(pCur[0][j] - mrow[j]);
            const float p1 = exp2_hw(pCur[1][j] - mrow[j]);
            pCur[0][j] = p0;
            pCur[1][j] = p1;
            lrow[j] += p0 + p1;
        }

        // ---- P -> per-wave LDS -> A-frag ----
        #pragma unroll
        for (int nn = 0; nn < 2; ++nn)
            #pragma unroll
            for (int j = 0; j < 4; ++j)
                Ps[wid][l4 * 4 + j][nn * 16 + l15] = (_Float16)pCur[nn][j];
        asm volatile("s_waitcnt lgkmcnt(0)" ::: "memory");
        __builtin_amdgcn_sched_barrier(0);

        // ---- O += P V(t) (chunked V: conflict-free) ----
        const f16x8 pf = *(const f16x8*)(&Ps[wid][l15][l4 * 8]);
        #pragma unroll
        for (int nd = 0; nd < 12; ++nd) {
            const f16x8 vfr = *(const f16x8*)(vRead + (((size_t)l4 * 192 + nd * 16 + l15) << 3));
            Oacc[nd] = mfma16(pf, vfr, Oacc[nd]);
        }
        __builtin_amdgcn_s_setprio(0);

        // rotate buffers: (read, stage, dead) <- (stage, dead, read)
        const _Float16* oldRead = kRead;
        kRead  = kStage;
        kStage = kDead;
        kDead  = (_Float16*)oldRead;
        const _Float16* ov = vRead;
        vRead  = vStage;
        vStage = (_Float16*)ov;
    };

    for (int t2 = 0; t2 < 64; t2 += 2) {
        body(t2,     pA, pB);
        body(t2 + 1, pB, pA);
    }

    // epilogue: reduce lrow across 16-lane key group, write 256-row X image
    #pragma unroll
    for (int j = 0; j < 4; ++j) {
        float s = lrow[j];
        s += __shfl_xor(s, 1);
        s += __shfl_xor(s, 2);
        s += __shfl_xor(s, 4);
        s += __shfl_xor(s, 8);
        lrow[j] = s;
    }
    const int b = bh >> 2;
    const int h = bh & 3;
    #pragma unroll
    for (int j = 0; j < 4; ++j) {
        const float inv = 1.f / lrow[j];
        const int qrow = q0 + l4 * 4 + j;
        const int gr   = b * SEQ + qrow;
        const int mt   = gr >> 8;
        const int rr   = gr & 255;
        #pragma unroll
        for (int nd = 0; nd < 12; ++nd) {
            const int gc = h * HD + nd * 16 + l15;
            const int t  = gc >> 6;
            const int cc = gc & 63;
            Ximg[((size_t)(mt * 12 + t) * 256 + rr) * 64 + (cc ^ ((rr & 7) << 3))] =
                (_Float16)(Oacc[nd][j] * inv);
        }
    }
}

// ---------------------------------------------------------------------------
extern "C" void kernel_launch(void* const* d_in, const int* in_sizes, int n_in,
                              void* d_out, int out_size, void* d_ws, size_t ws_size,
                              hipStream_t stream)
{
    const float* q  = (const float*)d_in[0];
    const float* k  = (const float*)d_in[1];
    const float* v  = (const float*)d_in[2];
    const float* Wq = (const float*)d_in[3];
    const float* Wk = (const float*)d_in[4];
    const float* Wv = (const float*)d_in[5];
    const float* Wp = (const float*)d_in[6];
    const float* bp = (const float*)d_in[7];

    const size_t HSZ  = (size_t)NBATCH * NH * SEQ * HD;  // 12,582,912
    const size_t WIMG = 4 * 12 * 12288;                  // 589,824 halves
    _Float16* Qh    = (_Float16*)d_ws;
    _Float16* KVimg = Qh + HSZ;          // 2*HSZ halves
    _Float16* Ximg  = KVimg + 2 * HSZ;
    _Float16* Wpimg = Ximg + HSZ;        // ~101.8 MB total ws
    _Float16* Wqimg = (_Float16*)d_out;  // d_out scratch until final GEMM
    _Float16* Wkimg = Wqimg + WIMG;
    _Float16* Wvimg = Wkimg + WIMG;

    cvt_w<<<dim3(576, 4), dim3(256), 0, stream>>>(Wq, Wk, Wv, Wp,
                                                  Wqimg, Wkimg, Wvimg, Wpimg);
    dim3 g8(64, 4), b8(512);
    gemm_p8<0><<<g8, b8, 0, stream>>>(q, Wqimg, Qh, SCALE_F * LOG2E);
    gemm_p8<1><<<g8, b8, 0, stream>>>(k, Wkimg, KVimg, 1.0f);
    gemm_p8<3><<<g8, b8, 0, stream>>>(v, Wvimg, KVimg, 1.0f);
    attn9<<<dim3(512), dim3(512), 0, stream>>>(Qh, KVimg, Ximg);
    gemm_x8<<<g8, b8, 0, stream>>>(Ximg, Wpimg, (float*)d_out, bp);
}

// Round 13
// 254.390 us; speedup vs baseline: 1.0437x; 1.0437x over previous
//
#include <hip/hip_runtime.h>
#include <hip/hip_fp16.h>

#define DIMC 768
#define NH 4
#define HD 192
#define SEQ 2048
#define NBATCH 8
#define SCALE_F 0.07216878364870323f  /* 192^-0.5 */
#define LOG2E   1.4426950408889634f
#define DEFER_THR 8.0f                /* log2-domain defer-max threshold */

typedef _Float16 f16x8 __attribute__((ext_vector_type(8)));
typedef _Float16 f16x4 __attribute__((ext_vector_type(4)));
typedef float    f32x4 __attribute__((ext_vector_type(4)));

__device__ __forceinline__ f32x4 mfma16(f16x8 a, f16x8 b, f32x4 c) {
    return __builtin_amdgcn_mfma_f32_16x16x32_f16(a, b, c, 0, 0, 0);
}
__device__ __forceinline__ void gl16(const void* g, void* l) {
    __builtin_amdgcn_global_load_lds(
        (const __attribute__((address_space(1))) unsigned int*)g,
        (__attribute__((address_space(3))) unsigned int*)l, 16, 0, 0);
}
__device__ __forceinline__ float exp2_hw(float x) {
    return __builtin_amdgcn_exp2f(x);
}

// ---------------------------------------------------------------------------
// cvt_w: fp32 W[768][768] -> fp16 pre-swizzled 192-row tile images.
// idx = ((nt*12 + t)*192 + rr)*64 + (cc ^ ((rr&7)<<3)).
// ---------------------------------------------------------------------------
__global__ __launch_bounds__(256)
void cvt_w(const float* __restrict__ w0, const float* __restrict__ w1,
           const float* __restrict__ w2, const float* __restrict__ w3,
           _Float16* __restrict__ o0, _Float16* __restrict__ o1,
           _Float16* __restrict__ o2, _Float16* __restrict__ o3)
{
    const float* src = (blockIdx.y == 0) ? w0 : (blockIdx.y == 1) ? w1
                     : (blockIdx.y == 2) ? w2 : w3;
    _Float16* dst = (blockIdx.y == 0) ? o0 : (blockIdx.y == 1) ? o1
                  : (blockIdx.y == 2) ? o2 : o3;
    const int e   = blockIdx.x * 256 + threadIdx.x;
    const int row = e / 192;
    const int col = (e - row * 192) * 4;
    const float4 v = *(const float4*)(src + (size_t)row * DIMC + col);
    const int nt = row / 192, rr = row - nt * 192;
    const int t  = col >> 6,  cc = col & 63;
    f16x4 h = {(_Float16)v.x, (_Float16)v.y, (_Float16)v.z, (_Float16)v.w};
    *(f16x4*)(dst + ((size_t)(nt * 12 + t) * 192 + rr) * 64 + (cc ^ ((rr & 7) << 3))) = h;
}

// ---------------------------------------------------------------------------
// 8-phase 256x192 GEMM helpers: 8 waves (2M x 4N), wave tile 128x48 (NF=3).
// ---------------------------------------------------------------------------
__device__ __forceinline__ void phase_reads(const _Float16* As, const _Float16* Bs,
                                            int wr, int wc, int l15, int l4, int q,
                                            f16x8 af[2][2], f16x8 bf[2][3], bool loadB)
{
    #pragma unroll
    for (int ks = 0; ks < 2; ++ks) {
        const int cb = ks * 32 + l4 * 8;
        #pragma unroll
        for (int mm = 0; mm < 2; ++mm) {
            const int row = wr * 128 + (q * 2 + mm) * 16 + l15;
            af[ks][mm] = *(const f16x8*)(As + (size_t)row * 64 + (cb ^ ((row & 7) << 3)));
        }
        if (loadB) {
            #pragma unroll
            for (int n = 0; n < 3; ++n) {
                const int row = wc * 48 + n * 16 + l15;
                bf[ks][n] = *(const f16x8*)(Bs + (size_t)row * 64 + (cb ^ ((row & 7) << 3)));
            }
        }
    }
}
__device__ __forceinline__ void phase_mfma(int q, f16x8 af[2][2], f16x8 bf[2][3],
                                           f32x4 acc[8][3])
{
    __builtin_amdgcn_s_barrier();
    asm volatile("s_waitcnt lgkmcnt(0)" ::: "memory");
    __builtin_amdgcn_s_setprio(1);
    #pragma unroll
    for (int ks = 0; ks < 2; ++ks)
        #pragma unroll
        for (int mm = 0; mm < 2; ++mm)
            #pragma unroll
            for (int n = 0; n < 3; ++n)
                acc[q * 2 + mm][n] = mfma16(af[ks][mm], bf[ks][n], acc[q * 2 + mm][n]);
    __builtin_amdgcn_s_setprio(0);
}

// ---------------------------------------------------------------------------
// Fused projection GEMM (8-phase, 256x192): ONE launch, grid (64, 12).
// which = blockIdx.y>>2 selects {q,k,v} input + output + scale;
// sub = blockIdx.y&3 is the head (192-col slab). Weight images contiguous:
// Wt = Wall + blockIdx.y*12*12288. Body identical to r11's gemm_p8.
// ---------------------------------------------------------------------------
__global__ __launch_bounds__(512, 2)
void gemm_pf(const float* __restrict__ qA, const float* __restrict__ kA,
             const float* __restrict__ vA, const _Float16* __restrict__ Wall,
             _Float16* __restrict__ Qh, _Float16* __restrict__ KVimg, float qs)
{
    __shared__ __attribute__((aligned(16))) _Float16 Abuf[2][16384];
    __shared__ __attribute__((aligned(16))) _Float16 Bbuf[2][12288];

    const int tid  = threadIdx.x;
    const int wid  = tid >> 6;
    const int lane = tid & 63;
    const int l15  = lane & 15;
    const int l4   = lane >> 4;
    const int wr   = wid >> 2;
    const int wc   = wid & 3;
    const int m0   = blockIdx.x * 256;
    const int y    = blockIdx.y;
    const int which = y >> 2;
    const int nt    = y & 3;

    const float* A = (which == 0) ? qA : (which == 1) ? kA : vA;
    const unsigned char* Wt = (const unsigned char*)(Wall + (size_t)y * 12 * 12288);

    f32x4 acc[8][3];
    #pragma unroll
    for (int m = 0; m < 8; ++m)
        #pragma unroll
        for (int n = 0; n < 3; ++n)
            acc[m][n] = (f32x4){0.f, 0.f, 0.f, 0.f};

    float4 rA[8];
    auto loadA = [&](int t) {
        #pragma unroll
        for (int p = 0; p < 8; ++p) {
            const int linear = p * 512 + tid;
            const int row = linear >> 4, qc = (linear & 15) * 4;
            rA[p] = *(const float4*)(A + (size_t)(m0 + row) * DIMC + t * 64 + qc);
        }
    };
    auto writeA = [&](int buf) {
        #pragma unroll
        for (int p = 0; p < 8; ++p) {
            const int linear = p * 512 + tid;
            const int row = linear >> 4, qc = (linear & 15) * 4;
            f16x4 h = {(_Float16)rA[p].x, (_Float16)rA[p].y,
                       (_Float16)rA[p].z, (_Float16)rA[p].w};
            *(f16x4*)(&Abuf[buf][row * 64 + (qc ^ ((row & 7) << 3))]) = h;
        }
    };
    auto stageB = [&](int t) {
        const unsigned char* src = Wt + (size_t)t * 24576;
        #pragma unroll
        for (int u = 0; u < 3; ++u)
            gl16(src + u * 8192 + tid * 16, &Bbuf[t & 1][u * 4096 + tid * 8]);
    };

    loadA(0);
    stageB(0);
    asm volatile("s_waitcnt vmcnt(3)" ::: "memory");
    writeA(0);
    loadA(1);
    asm volatile("s_waitcnt vmcnt(8)" ::: "memory");
    asm volatile("s_waitcnt lgkmcnt(0)" ::: "memory");
    __builtin_amdgcn_s_barrier();

    for (int t = 0; t < 12; ++t) {
        const _Float16* As = &Abuf[t & 1][0];
        const _Float16* Bs = &Bbuf[t & 1][0];
        f16x8 af[2][2], bf[2][3];

        phase_reads(As, Bs, wr, wc, l15, l4, 0, af, bf, true);
        if (t < 11) stageB(t + 1);
        phase_mfma(0, af, bf, acc);
        __builtin_amdgcn_s_barrier();

        phase_reads(As, Bs, wr, wc, l15, l4, 1, af, bf, false);
        phase_mfma(1, af, bf, acc);
        __builtin_amdgcn_s_barrier();

        phase_reads(As, Bs, wr, wc, l15, l4, 2, af, bf, false);
        if (t < 11) {
            asm volatile("s_waitcnt vmcnt(3)" ::: "memory");
            writeA((t + 1) & 1);
            if (t < 10) loadA(t + 2);
        }
        phase_mfma(2, af, bf, acc);
        __builtin_amdgcn_s_barrier();

        phase_reads(As, Bs, wr, wc, l15, l4, 3, af, bf, false);
        phase_mfma(3, af, bf, acc);
        if (t < 10)       asm volatile("s_waitcnt vmcnt(8)" ::: "memory");
        else if (t == 10) asm volatile("s_waitcnt vmcnt(0)" ::: "memory");
        __builtin_amdgcn_s_barrier();
    }

    // epilogue: h = nt; Q linear (scaled), K swizzled, V chunked
    const float scale = (which == 0) ? qs : 1.0f;
    #pragma unroll
    for (int m = 0; m < 8; ++m) {
        const int rbase = m0 + wr * 128 + m * 16 + l4 * 4;
        #pragma unroll
        for (int n = 0; n < 3; ++n) {
            const int d = wc * 48 + n * 16 + l15;
            #pragma unroll
            for (int j = 0; j < 4; ++j) {
                const int r  = rbase + j;
                const int b  = r >> 11;
                const int nn = r & (SEQ - 1);
                if (which == 0) {
                    Qh[((size_t)(b * NH + nt) * SEQ + nn) * HD + d] =
                        (_Float16)(acc[m][n][j] * scale);
                } else {
                    const int kt  = nn >> 5;
                    const int key = nn & 31;
                    const size_t tb = ((size_t)(b * NH + nt) * 64 + kt) * 12288;
                    size_t idx;
                    if (which == 1)
                        idx = tb + (size_t)key * HD + (d ^ ((key & 7) << 3));
                    else
                        idx = tb + 6144 + (((size_t)(key >> 3) * 192 + d) << 3) + (key & 7);
                    KVimg[idx] = (_Float16)acc[m][n][j];
                }
            }
        }
    }
}

// ---------------------------------------------------------------------------
// Final GEMM (8-phase, 256x192, grid 64x4). Verbatim r11.
// ---------------------------------------------------------------------------
__global__ __launch_bounds__(512, 2)
void gemm_x8(const _Float16* __restrict__ Ximg, const _Float16* __restrict__ Wimg,
             float* __restrict__ out, const float* __restrict__ bias)
{
    __shared__ __attribute__((aligned(16))) _Float16 Abuf[2][16384];
    __shared__ __attribute__((aligned(16))) _Float16 Bbuf[2][12288];

    const int tid  = threadIdx.x;
    const int wid  = tid >> 6;
    const int lane = tid & 63;
    const int l15  = lane & 15;
    const int l4   = lane >> 4;
    const int wr   = wid >> 2;
    const int wc   = wid & 3;
    const int mt   = blockIdx.x;
    const int nt   = blockIdx.y;

    const unsigned char* Xt = (const unsigned char*)(Ximg + (size_t)mt * 12 * 16384);
    const unsigned char* Wt = (const unsigned char*)(Wimg + (size_t)nt * 12 * 12288);

    f32x4 acc[8][3];
    #pragma unroll
    for (int m = 0; m < 8; ++m)
        #pragma unroll
        for (int n = 0; n < 3; ++n)
            acc[m][n] = (f32x4){0.f, 0.f, 0.f, 0.f};

    auto stageAB = [&](int t) {
        const unsigned char* sa = Xt + (size_t)t * 32768;
        const unsigned char* sb = Wt + (size_t)t * 24576;
        #pragma unroll
        for (int u = 0; u < 4; ++u)
            gl16(sa + u * 8192 + tid * 16, &Abuf[t & 1][u * 4096 + tid * 8]);
        #pragma unroll
        for (int u = 0; u < 3; ++u)
            gl16(sb + u * 8192 + tid * 16, &Bbuf[t & 1][u * 4096 + tid * 8]);
    };

    stageAB(0);
    asm volatile("s_waitcnt vmcnt(0)" ::: "memory");
    __builtin_amdgcn_s_barrier();

    for (int t = 0; t < 12; ++t) {
        const _Float16* As = &Abuf[t & 1][0];
        const _Float16* Bs = &Bbuf[t & 1][0];
        f16x8 af[2][2], bf[2][3];

        phase_reads(As, Bs, wr, wc, l15, l4, 0, af, bf, true);
        if (t < 11) stageAB(t + 1);
        phase_mfma(0, af, bf, acc);
        __builtin_amdgcn_s_barrier();

        phase_reads(As, Bs, wr, wc, l15, l4, 1, af, bf, false);
        phase_mfma(1, af, bf, acc);
        __builtin_amdgcn_s_barrier();

        phase_reads(As, Bs, wr, wc, l15, l4, 2, af, bf, false);
        phase_mfma(2, af, bf, acc);
        __builtin_amdgcn_s_barrier();

        phase_reads(As, Bs, wr, wc, l15, l4, 3, af, bf, false);
        phase_mfma(3, af, bf, acc);
        if (t < 11) asm volatile("s_waitcnt vmcnt(0)" ::: "memory");
        __builtin_amdgcn_s_barrier();
    }

    #pragma unroll
    for (int m = 0; m < 8; ++m) {
        const int rbase = mt * 256 + wr * 128 + m * 16 + l4 * 4;
        #pragma unroll
        for (int n = 0; n < 3; ++n) {
            const int c = nt * 192 + wc * 48 + n * 16 + l15;
            const float bv = bias[c];
            #pragma unroll
            for (int j = 0; j < 4; ++j)
                out[(size_t)(rbase + j) * DIMC + c] = acc[m][n][j] + bv;
        }
    }
}

// ---------------------------------------------------------------------------
// Flash attention (verbatim r11 attn7 — proven 126.5us local optimum):
// 512 thr = 8 waves x 16 q-rows, KVBLK=32, 2 blocks/CU, gl16 dbuf KV,
// vmcnt(3) counted, defer-max softmax, per-lane lrow, chunked V.
// ---------------------------------------------------------------------------
__global__ __launch_bounds__(512, 4)
void attn7(const _Float16* __restrict__ Qh, const _Float16* __restrict__ KVimg,
           _Float16* __restrict__ Ximg)
{
    __shared__ __attribute__((aligned(16))) _Float16 KV[2][12288]; // K:0..6144, V:6144..
    __shared__ __attribute__((aligned(16))) _Float16 Ps[8][16][40];

    const int tid  = threadIdx.x;
    const int wid  = tid >> 6;
    const int lane = tid & 63;
    const int l15  = lane & 15;
    const int l4   = lane >> 4;

    const int bid   = blockIdx.x;
    const int local = bid >> 3;
    const int bh    = (bid & 7) * 4 + (local >> 4);
    const int qt    = local & 15;

    const unsigned char* KVt = (const unsigned char*)KVimg + (size_t)bh * 64 * 24576;

    #pragma unroll
    for (int s = 0; s < 3; ++s)
        gl16(KVt + (size_t)(s * 512 + tid) * 16, &KV[0][(size_t)(s * 512 + tid) * 8]);

    const int q0 = qt * 128 + wid * 16;
    const size_t qbase = (size_t)bh * SEQ * HD;
    f16x8 qf[6];
    #pragma unroll
    for (int kk = 0; kk < 6; ++kk)
        qf[kk] = *(const f16x8*)(Qh + qbase + (size_t)(q0 + l15) * HD + kk * 32 + l4 * 8);

    f32x4 Oacc[12];
    #pragma unroll
    for (int nd = 0; nd < 12; ++nd)
        Oacc[nd] = (f32x4){0.f, 0.f, 0.f, 0.f};
    float mrow[4], lrow[4];
    #pragma unroll
    for (int j = 0; j < 4; ++j) { mrow[j] = -1e30f; lrow[j] = 0.f; }

    for (int kt = 0; kt < SEQ / 32; ++kt) {
        const int cur = kt & 1;
        if (kt < SEQ / 32 - 1) {
            const unsigned char* KVn = KVt + (size_t)(kt + 1) * 24576;
            #pragma unroll
            for (int s = 0; s < 3; ++s)
                gl16(KVn + (size_t)(s * 512 + tid) * 16,
                     &KV[cur ^ 1][(size_t)(s * 512 + tid) * 8]);
            asm volatile("s_waitcnt vmcnt(3)" ::: "memory");
        } else {
            asm volatile("s_waitcnt vmcnt(0)" ::: "memory");
        }
        __builtin_amdgcn_s_barrier();
        __builtin_amdgcn_sched_barrier(0);

        const _Float16* Kc = &KV[cur][0];
        const _Float16* Vc = &KV[cur][6144];

        // ---- S = Q K^T ----
        f32x4 sacc[2];
        sacc[0] = (f32x4){0.f, 0.f, 0.f, 0.f};
        sacc[1] = (f32x4){0.f, 0.f, 0.f, 0.f};
        __builtin_amdgcn_s_setprio(1);
        #pragma unroll
        for (int kk = 0; kk < 6; ++kk) {
            const int cb = (kk * 32 + l4 * 8) ^ ((l15 & 7) << 3);
            #pragma unroll
            for (int nn = 0; nn < 2; ++nn) {
                const f16x8 kf = *(const f16x8*)(Kc + (size_t)(nn * 16 + l15) * HD + cb);
                sacc[nn] = mfma16(qf[kk], kf, sacc[nn]);
            }
        }
        __builtin_amdgcn_s_setprio(0);

        // ---- defer-max online softmax ----
        float lm[4];
        bool need = false;
        #pragma unroll
        for (int j = 0; j < 4; ++j) {
            lm[j] = fmaxf(sacc[0][j], sacc[1][j]);
            need |= (lm[j] > mrow[j] + DEFER_THR);
        }
        if (__any(need)) {
            #pragma unroll
            for (int j = 0; j < 4; ++j) {
                float v = lm[j];
                v = fmaxf(v, __shfl_xor(v, 1));
                v = fmaxf(v, __shfl_xor(v, 2));
                v = fmaxf(v, __shfl_xor(v, 4));
                v = fmaxf(v, __shfl_xor(v, 8));
                const float mnew = fmaxf(mrow[j], v);
                const float f    = exp2_hw(mrow[j] - mnew);
                mrow[j] = mnew;
                lrow[j] *= f;
                #pragma unroll
                for (int nd = 0; nd < 12; ++nd)
                    Oacc[nd][j] *= f;
            }
        }
        #pragma unroll
        for (int j = 0; j < 4; ++j) {
            const float p0 = exp2_hw(sacc[0][j] - mrow[j]);
            const float p1 = exp2_hw(sacc[1][j] - mrow[j]);
            sacc[0][j] = p0;
            sacc[1][j] = p1;
            lrow[j] += p0 + p1;
        }

        // ---- P -> per-wave LDS -> A-frag ----
        #pragma unroll
        for (int nn = 0; nn < 2; ++nn)
            #pragma unroll
            for (int j = 0; j < 4; ++j)
                Ps[wid][l4 * 4 + j][nn * 16 + l15] = (_Float16)sacc[nn][j];
        asm volatile("s_waitcnt lgkmcnt(0)" ::: "memory");
        __builtin_amdgcn_sched_barrier(0);

        // ---- O += P V (chunked V: conflict-free) ----
        const f16x8 pf = *(const f16x8*)(&Ps[wid][l15][l4 * 8]);
        __builtin_amdgcn_s_setprio(1);
        #pragma unroll
        for (int nd = 0; nd < 12; ++nd) {
            const f16x8 vfr = *(const f16x8*)(Vc + (((size_t)l4 * 192 + nd * 16 + l15) << 3));
            Oacc[nd] = mfma16(pf, vfr, Oacc[nd]);
        }
        __builtin_amdgcn_s_setprio(0);

        __builtin_amdgcn_s_barrier();
        __builtin_amdgcn_sched_barrier(0);
    }

    // epilogue: reduce lrow, write 256-row-tile X image
    #pragma unroll
    for (int j = 0; j < 4; ++j) {
        float s = lrow[j];
        s += __shfl_xor(s, 1);
        s += __shfl_xor(s, 2);
        s += __shfl_xor(s, 4);
        s += __shfl_xor(s, 8);
        lrow[j] = s;
    }
    const int b = bh >> 2;
    const int h = bh & 3;
    #pragma unroll
    for (int j = 0; j < 4; ++j) {
        const float inv = 1.f / lrow[j];
        const int qrow = q0 + l4 * 4 + j;
        const int gr   = b * SEQ + qrow;
        const int mt   = gr >> 8;
        const int rr   = gr & 255;
        #pragma unroll
        for (int nd = 0; nd < 12; ++nd) {
            const int gc = h * HD + nd * 16 + l15;
            const int t  = gc >> 6;
            const int cc = gc & 63;
            Ximg[((size_t)(mt * 12 + t) * 256 + rr) * 64 + (cc ^ ((rr & 7) << 3))] =
                (_Float16)(Oacc[nd][j] * inv);
        }
    }
}

// ---------------------------------------------------------------------------
extern "C" void kernel_launch(void* const* d_in, const int* in_sizes, int n_in,
                              void* d_out, int out_size, void* d_ws, size_t ws_size,
                              hipStream_t stream)
{
    const float* q  = (const float*)d_in[0];
    const float* k  = (const float*)d_in[1];
    const float* v  = (const float*)d_in[2];
    const float* Wq = (const float*)d_in[3];
    const float* Wk = (const float*)d_in[4];
    const float* Wv = (const float*)d_in[5];
    const float* Wp = (const float*)d_in[6];
    const float* bp = (const float*)d_in[7];

    const size_t HSZ  = (size_t)NBATCH * NH * SEQ * HD;  // 12,582,912
    const size_t WIMG = 4 * 12 * 12288;                  // 589,824 halves
    _Float16* Qh    = (_Float16*)d_ws;
    _Float16* KVimg = Qh + HSZ;          // 2*HSZ halves
    _Float16* Ximg  = KVimg + 2 * HSZ;
    _Float16* Wpimg = Ximg + HSZ;        // ~101.8 MB total ws
    _Float16* Wqimg = (_Float16*)d_out;  // 3 contiguous images in d_out scratch
    _Float16* Wkimg = Wqimg + WIMG;
    _Float16* Wvimg = Wkimg + WIMG;

    cvt_w<<<dim3(576, 4), dim3(256), 0, stream>>>(Wq, Wk, Wv, Wp,
                                                  Wqimg, Wkimg, Wvimg, Wpimg);
    gemm_pf<<<dim3(64, 12), dim3(512), 0, stream>>>(q, k, v, Wqimg, Qh, KVimg,
                                                    SCALE_F * LOG2E);
    attn7<<<dim3(512), dim3(512), 0, stream>>>(Qh, KVimg, Ximg);
    gemm_x8<<<dim3(64, 4), dim3(512), 0, stream>>>(Ximg, Wpimg, (float*)d_out, bp);
}

// Round 14
// 248.984 us; speedup vs baseline: 1.0663x; 1.0217x over previous
//
#include <hip/hip_runtime.h>
#include <hip/hip_fp16.h>

#define DIMC 768
#define NH 4
#define HD 192
#define SEQ 2048
#define NBATCH 8
#define SCALE_F 0.07216878364870323f  /* 192^-0.5 */
#define LOG2E   1.4426950408889634f
#define DEFER_THR 8.0f                /* log2-domain defer-max threshold */

typedef _Float16 f16x8 __attribute__((ext_vector_type(8)));
typedef _Float16 f16x4 __attribute__((ext_vector_type(4)));
typedef float    f32x4 __attribute__((ext_vector_type(4)));

__device__ __forceinline__ f32x4 mfma16(f16x8 a, f16x8 b, f32x4 c) {
    return __builtin_amdgcn_mfma_f32_16x16x32_f16(a, b, c, 0, 0, 0);
}
__device__ __forceinline__ void gl16(const void* g, void* l) {
    __builtin_amdgcn_global_load_lds(
        (const __attribute__((address_space(1))) unsigned int*)g,
        (__attribute__((address_space(3))) unsigned int*)l, 16, 0, 0);
}
__device__ __forceinline__ float exp2_hw(float x) {
    return __builtin_amdgcn_exp2f(x);
}

// ---------------------------------------------------------------------------
// cvt_w: fp32 W[768][768] -> fp16 pre-swizzled 192-row tile images.
// idx = ((nt*12 + t)*192 + rr)*64 + (cc ^ ((rr&7)<<3)).   (verbatim r11)
// ---------------------------------------------------------------------------
__global__ __launch_bounds__(256)
void cvt_w(const float* __restrict__ w0, const float* __restrict__ w1,
           const float* __restrict__ w2, const float* __restrict__ w3,
           _Float16* __restrict__ o0, _Float16* __restrict__ o1,
           _Float16* __restrict__ o2, _Float16* __restrict__ o3)
{
    const float* src = (blockIdx.y == 0) ? w0 : (blockIdx.y == 1) ? w1
                     : (blockIdx.y == 2) ? w2 : w3;
    _Float16* dst = (blockIdx.y == 0) ? o0 : (blockIdx.y == 1) ? o1
                  : (blockIdx.y == 2) ? o2 : o3;
    const int e   = blockIdx.x * 256 + threadIdx.x;
    const int row = e / 192;
    const int col = (e - row * 192) * 4;
    const float4 v = *(const float4*)(src + (size_t)row * DIMC + col);
    const int nt = row / 192, rr = row - nt * 192;
    const int t  = col >> 6,  cc = col & 63;
    f16x4 h = {(_Float16)v.x, (_Float16)v.y, (_Float16)v.z, (_Float16)v.w};
    *(f16x4*)(dst + ((size_t)(nt * 12 + t) * 192 + rr) * 64 + (cc ^ ((rr & 7) << 3))) = h;
}

// ---------------------------------------------------------------------------
// 2-phase 128x192 GEMM helpers: 8 waves (2M x 4N), wave tile 64x48.
// As: [128][64], Bs: [192][64], swizzle col ^ ((row&7)<<3).
// Phase q in {0,1}: m-frags 2q, 2q+1. Same per-phase shape as r11 (12 MFMA).
// ---------------------------------------------------------------------------
__device__ __forceinline__ void phase_reads2(const _Float16* As, const _Float16* Bs,
                                             int wr, int wc, int l15, int l4, int q,
                                             f16x8 af[2][2], f16x8 bf[2][3], bool loadB)
{
    #pragma unroll
    for (int ks = 0; ks < 2; ++ks) {
        const int cb = ks * 32 + l4 * 8;
        #pragma unroll
        for (int mm = 0; mm < 2; ++mm) {
            const int row = wr * 64 + (q * 2 + mm) * 16 + l15;
            af[ks][mm] = *(const f16x8*)(As + (size_t)row * 64 + (cb ^ ((row & 7) << 3)));
        }
        if (loadB) {
            #pragma unroll
            for (int n = 0; n < 3; ++n) {
                const int row = wc * 48 + n * 16 + l15;
                bf[ks][n] = *(const f16x8*)(Bs + (size_t)row * 64 + (cb ^ ((row & 7) << 3)));
            }
        }
    }
}
__device__ __forceinline__ void phase_mfma2(int q, f16x8 af[2][2], f16x8 bf[2][3],
                                            f32x4 acc[4][3])
{
    __builtin_amdgcn_s_barrier();
    asm volatile("s_waitcnt lgkmcnt(0)" ::: "memory");
    __builtin_amdgcn_s_setprio(1);
    #pragma unroll
    for (int ks = 0; ks < 2; ++ks)
        #pragma unroll
        for (int mm = 0; mm < 2; ++mm)
            #pragma unroll
            for (int n = 0; n < 3; ++n)
                acc[q * 2 + mm][n] = mfma16(af[ks][mm], bf[ks][n], acc[q * 2 + mm][n]);
    __builtin_amdgcn_s_setprio(0);
}

// ---------------------------------------------------------------------------
// Projection GEMM (2-phase, 128x192, grid 128x4 = 512 blocks = 2/CU, 80KB LDS):
// A fp32 reg-staged (cvt->swizzled ds_write), B gl16 from 192-tile image.
// MODE 0: Q linear [bh][n][d] scaled; MODE 1: K half of KVimg;
// MODE 3: V half of KVimg chunked [c][d][8key].  (KVBLK=32; h = nt)
// ---------------------------------------------------------------------------
template<int MODE>
__global__ __launch_bounds__(512, 4)
void gemm_p2(const float* __restrict__ A, const _Float16* __restrict__ Wimg,
             _Float16* __restrict__ Y, float scale)
{
    __shared__ __attribute__((aligned(16))) _Float16 Abuf[2][8192];
    __shared__ __attribute__((aligned(16))) _Float16 Bbuf[2][12288];

    const int tid  = threadIdx.x;
    const int wid  = tid >> 6;
    const int lane = tid & 63;
    const int l15  = lane & 15;
    const int l4   = lane >> 4;
    const int wr   = wid >> 2;
    const int wc   = wid & 3;
    const int m0   = blockIdx.x * 128;
    const int nt   = blockIdx.y;

    const unsigned char* Wt = (const unsigned char*)(Wimg + (size_t)nt * 12 * 12288);

    f32x4 acc[4][3];
    #pragma unroll
    for (int m = 0; m < 4; ++m)
        #pragma unroll
        for (int n = 0; n < 3; ++n)
            acc[m][n] = (f32x4){0.f, 0.f, 0.f, 0.f};

    float4 rA[4];
    auto loadA = [&](int t) {
        #pragma unroll
        for (int p = 0; p < 4; ++p) {
            const int linear = p * 512 + tid;
            const int row = linear >> 4, qc = (linear & 15) * 4;
            rA[p] = *(const float4*)(A + (size_t)(m0 + row) * DIMC + t * 64 + qc);
        }
    };
    auto writeA = [&](int buf) {
        #pragma unroll
        for (int p = 0; p < 4; ++p) {
            const int linear = p * 512 + tid;
            const int row = linear >> 4, qc = (linear & 15) * 4;
            f16x4 h = {(_Float16)rA[p].x, (_Float16)rA[p].y,
                       (_Float16)rA[p].z, (_Float16)rA[p].w};
            *(f16x4*)(&Abuf[buf][row * 64 + (qc ^ ((row & 7) << 3))]) = h;
        }
    };
    auto stageB = [&](int t) {
        const unsigned char* src = Wt + (size_t)t * 24576;
        #pragma unroll
        for (int u = 0; u < 3; ++u)
            gl16(src + u * 8192 + tid * 16, &Bbuf[t & 1][u * 4096 + tid * 8]);
    };

    // prologue: A(0)[4] + B(0)[3]; A gate; write; A(1); B gate
    loadA(0);
    stageB(0);
    asm volatile("s_waitcnt vmcnt(3)" ::: "memory");   // A(0) landed (3 B fly)
    writeA(0);
    loadA(1);
    asm volatile("s_waitcnt vmcnt(4)" ::: "memory");   // B(0) landed (4 A fly)
    asm volatile("s_waitcnt lgkmcnt(0)" ::: "memory");
    __builtin_amdgcn_s_barrier();

    for (int t = 0; t < 12; ++t) {
        const _Float16* As = &Abuf[t & 1][0];
        const _Float16* Bs = &Bbuf[t & 1][0];
        f16x8 af[2][2], bf[2][3];

        // p0: reads + stage B(t+1)
        phase_reads2(As, Bs, wr, wc, l15, l4, 0, af, bf, true);
        if (t < 11) stageB(t + 1);
        phase_mfma2(0, af, bf, acc);
        __builtin_amdgcn_s_barrier();

        // p1: reads + A(t+1) cvt/write + issue A(t+2)
        phase_reads2(As, Bs, wr, wc, l15, l4, 1, af, bf, false);
        if (t < 11) {
            asm volatile("s_waitcnt vmcnt(3)" ::: "memory");  // A(t+1) landed
            writeA((t + 1) & 1);
            if (t < 10) loadA(t + 2);
        }
        phase_mfma2(1, af, bf, acc);
        if (t < 10)       asm volatile("s_waitcnt vmcnt(4)" ::: "memory"); // B(t+1) done
        else if (t == 10) asm volatile("s_waitcnt vmcnt(0)" ::: "memory");
        __builtin_amdgcn_s_barrier();
    }

    // epilogue: h = nt, d = wc*48 + n*16 + l15
    #pragma unroll
    for (int m = 0; m < 4; ++m) {
        const int rbase = m0 + wr * 64 + m * 16 + l4 * 4;
        #pragma unroll
        for (int n = 0; n < 3; ++n) {
            const int d = wc * 48 + n * 16 + l15;
            #pragma unroll
            for (int j = 0; j < 4; ++j) {
                const int r  = rbase + j;
                const int b  = r >> 11;
                const int nn = r & (SEQ - 1);
                if (MODE == 0) {
                    Y[((size_t)(b * NH + nt) * SEQ + nn) * HD + d] =
                        (_Float16)(acc[m][n][j] * scale);
                } else {
                    const int kt  = nn >> 5;
                    const int key = nn & 31;
                    const size_t tb = ((size_t)(b * NH + nt) * 64 + kt) * 12288;
                    size_t idx;
                    if (MODE == 1)
                        idx = tb + (size_t)key * HD + (d ^ ((key & 7) << 3));
                    else
                        idx = tb + 6144 + (((size_t)(key >> 3) * 192 + d) << 3) + (key & 7);
                    Y[idx] = (_Float16)acc[m][n][j];
                }
            }
        }
    }
}

// ---------------------------------------------------------------------------
// Final GEMM (2-phase, 128x192, grid 128x4, 80KB LDS): out = Ximg@Wp.T + bias.
// A: 128-row slice of 256-row Ximg tile (contiguous) via gl16; B via gl16.
// ---------------------------------------------------------------------------
__global__ __launch_bounds__(512, 4)
void gemm_x2(const _Float16* __restrict__ Ximg, const _Float16* __restrict__ Wimg,
             float* __restrict__ out, const float* __restrict__ bias)
{
    __shared__ __attribute__((aligned(16))) _Float16 Abuf[2][8192];
    __shared__ __attribute__((aligned(16))) _Float16 Bbuf[2][12288];

    const int tid  = threadIdx.x;
    const int wid  = tid >> 6;
    const int lane = tid & 63;
    const int l15  = lane & 15;
    const int l4   = lane >> 4;
    const int wr   = wid >> 2;
    const int wc   = wid & 3;
    const int mt   = blockIdx.x;          // 128-row tile index
    const int nt   = blockIdx.y;

    // A source: rows [mt*128, mt*128+128) of the 256-row image tiles
    const unsigned char* Xt = (const unsigned char*)Ximg +
        (((size_t)(mt >> 1) * 12) * 256 + (size_t)(mt & 1) * 128) * 128;
    const unsigned char* Wt = (const unsigned char*)(Wimg + (size_t)nt * 12 * 12288);

    f32x4 acc[4][3];
    #pragma unroll
    for (int m = 0; m < 4; ++m)
        #pragma unroll
        for (int n = 0; n < 3; ++n)
            acc[m][n] = (f32x4){0.f, 0.f, 0.f, 0.f};

    auto stageAB = [&](int t) {
        const unsigned char* sa = Xt + (size_t)t * 32768;   // image tile stride 256*128B
        const unsigned char* sb = Wt + (size_t)t * 24576;
        #pragma unroll
        for (int u = 0; u < 2; ++u)
            gl16(sa + u * 8192 + tid * 16, &Abuf[t & 1][u * 4096 + tid * 8]);
        #pragma unroll
        for (int u = 0; u < 3; ++u)
            gl16(sb + u * 8192 + tid * 16, &Bbuf[t & 1][u * 4096 + tid * 8]);
    };

    stageAB(0);
    asm volatile("s_waitcnt vmcnt(0)" ::: "memory");
    __builtin_amdgcn_s_barrier();

    for (int t = 0; t < 12; ++t) {
        const _Float16* As = &Abuf[t & 1][0];
        const _Float16* Bs = &Bbuf[t & 1][0];
        f16x8 af[2][2], bf[2][3];

        phase_reads2(As, Bs, wr, wc, l15, l4, 0, af, bf, true);
        if (t < 11) stageAB(t + 1);
        phase_mfma2(0, af, bf, acc);
        __builtin_amdgcn_s_barrier();

        phase_reads2(As, Bs, wr, wc, l15, l4, 1, af, bf, false);
        phase_mfma2(1, af, bf, acc);
        if (t < 11) asm volatile("s_waitcnt vmcnt(0)" ::: "memory");
        __builtin_amdgcn_s_barrier();
    }

    #pragma unroll
    for (int m = 0; m < 4; ++m) {
        const int rbase = mt * 128 + wr * 64 + m * 16 + l4 * 4;
        #pragma unroll
        for (int n = 0; n < 3; ++n) {
            const int c = nt * 192 + wc * 48 + n * 16 + l15;
            const float bv = bias[c];
            #pragma unroll
            for (int j = 0; j < 4; ++j)
                out[(size_t)(rbase + j) * DIMC + c] = acc[m][n][j] + bv;
        }
    }
}

// ---------------------------------------------------------------------------
// Flash attention (verbatim r11 attn7 — proven 126.5us local optimum):
// 512 thr = 8 waves x 16 q-rows, KVBLK=32, 2 blocks/CU, gl16 dbuf KV,
// vmcnt(3) counted, defer-max softmax, per-lane lrow, chunked V.
// ---------------------------------------------------------------------------
__global__ __launch_bounds__(512, 4)
void attn7(const _Float16* __restrict__ Qh, const _Float16* __restrict__ KVimg,
           _Float16* __restrict__ Ximg)
{
    __shared__ __attribute__((aligned(16))) _Float16 KV[2][12288]; // K:0..6144, V:6144..
    __shared__ __attribute__((aligned(16))) _Float16 Ps[8][16][40];

    const int tid  = threadIdx.x;
    const int wid  = tid >> 6;
    const int lane = tid & 63;
    const int l15  = lane & 15;
    const int l4   = lane >> 4;

    const int bid   = blockIdx.x;
    const int local = bid >> 3;
    const int bh    = (bid & 7) * 4 + (local >> 4);
    const int qt    = local & 15;

    const unsigned char* KVt = (const unsigned char*)KVimg + (size_t)bh * 64 * 24576;

    #pragma unroll
    for (int s = 0; s < 3; ++s)
        gl16(KVt + (size_t)(s * 512 + tid) * 16, &KV[0][(size_t)(s * 512 + tid) * 8]);

    const int q0 = qt * 128 + wid * 16;
    const size_t qbase = (size_t)bh * SEQ * HD;
    f16x8 qf[6];
    #pragma unroll
    for (int kk = 0; kk < 6; ++kk)
        qf[kk] = *(const f16x8*)(Qh + qbase + (size_t)(q0 + l15) * HD + kk * 32 + l4 * 8);

    f32x4 Oacc[12];
    #pragma unroll
    for (int nd = 0; nd < 12; ++nd)
        Oacc[nd] = (f32x4){0.f, 0.f, 0.f, 0.f};
    float mrow[4], lrow[4];
    #pragma unroll
    for (int j = 0; j < 4; ++j) { mrow[j] = -1e30f; lrow[j] = 0.f; }

    for (int kt = 0; kt < SEQ / 32; ++kt) {
        const int cur = kt & 1;
        if (kt < SEQ / 32 - 1) {
            const unsigned char* KVn = KVt + (size_t)(kt + 1) * 24576;
            #pragma unroll
            for (int s = 0; s < 3; ++s)
                gl16(KVn + (size_t)(s * 512 + tid) * 16,
                     &KV[cur ^ 1][(size_t)(s * 512 + tid) * 8]);
            asm volatile("s_waitcnt vmcnt(3)" ::: "memory");
        } else {
            asm volatile("s_waitcnt vmcnt(0)" ::: "memory");
        }
        __builtin_amdgcn_s_barrier();
        __builtin_amdgcn_sched_barrier(0);

        const _Float16* Kc = &KV[cur][0];
        const _Float16* Vc = &KV[cur][6144];

        // ---- S = Q K^T ----
        f32x4 sacc[2];
        sacc[0] = (f32x4){0.f, 0.f, 0.f, 0.f};
        sacc[1] = (f32x4){0.f, 0.f, 0.f, 0.f};
        __builtin_amdgcn_s_setprio(1);
        #pragma unroll
        for (int kk = 0; kk < 6; ++kk) {
            const int cb = (kk * 32 + l4 * 8) ^ ((l15 & 7) << 3);
            #pragma unroll
            for (int nn = 0; nn < 2; ++nn) {
                const f16x8 kf = *(const f16x8*)(Kc + (size_t)(nn * 16 + l15) * HD + cb);
                sacc[nn] = mfma16(qf[kk], kf, sacc[nn]);
            }
        }
        __builtin_amdgcn_s_setprio(0);

        // ---- defer-max online softmax ----
        float lm[4];
        bool need = false;
        #pragma unroll
        for (int j = 0; j < 4; ++j) {
            lm[j] = fmaxf(sacc[0][j], sacc[1][j]);
            need |= (lm[j] > mrow[j] + DEFER_THR);
        }
        if (__any(need)) {
            #pragma unroll
            for (int j = 0; j < 4; ++j) {
                float v = lm[j];
                v = fmaxf(v, __shfl_xor(v, 1));
                v = fmaxf(v, __shfl_xor(v, 2));
                v = fmaxf(v, __shfl_xor(v, 4));
                v = fmaxf(v, __shfl_xor(v, 8));
                const float mnew = fmaxf(mrow[j], v);
                const float f    = exp2_hw(mrow[j] - mnew);
                mrow[j] = mnew;
                lrow[j] *= f;
                #pragma unroll
                for (int nd = 0; nd < 12; ++nd)
                    Oacc[nd][j] *= f;
            }
        }
        #pragma unroll
        for (int j = 0; j < 4; ++j) {
            const float p0 = exp2_hw(sacc[0][j] - mrow[j]);
            const float p1 = exp2_hw(sacc[1][j] - mrow[j]);
            sacc[0][j] = p0;
            sacc[1][j] = p1;
            lrow[j] += p0 + p1;
        }

        // ---- P -> per-wave LDS -> A-frag ----
        #pragma unroll
        for (int nn = 0; nn < 2; ++nn)
            #pragma unroll
            for (int j = 0; j < 4; ++j)
                Ps[wid][l4 * 4 + j][nn * 16 + l15] = (_Float16)sacc[nn][j];
        asm volatile("s_waitcnt lgkmcnt(0)" ::: "memory");
        __builtin_amdgcn_sched_barrier(0);

        // ---- O += P V (chunked V: conflict-free) ----
        const f16x8 pf = *(const f16x8*)(&Ps[wid][l15][l4 * 8]);
        __builtin_amdgcn_s_setprio(1);
        #pragma unroll
        for (int nd = 0; nd < 12; ++nd) {
            const f16x8 vfr = *(const f16x8*)(Vc + (((size_t)l4 * 192 + nd * 16 + l15) << 3));
            Oacc[nd] = mfma16(pf, vfr, Oacc[nd]);
        }
        __builtin_amdgcn_s_setprio(0);

        __builtin_amdgcn_s_barrier();
        __builtin_amdgcn_sched_barrier(0);
    }

    // epilogue: reduce lrow, write 256-row-tile X image
    #pragma unroll
    for (int j = 0; j < 4; ++j) {
        float s = lrow[j];
        s += __shfl_xor(s, 1);
        s += __shfl_xor(s, 2);
        s += __shfl_xor(s, 4);
        s += __shfl_xor(s, 8);
        lrow[j] = s;
    }
    const int b = bh >> 2;
    const int h = bh & 3;
    #pragma unroll
    for (int j = 0; j < 4; ++j) {
        const float inv = 1.f / lrow[j];
        const int qrow = q0 + l4 * 4 + j;
        const int gr   = b * SEQ + qrow;
        const int mt   = gr >> 8;
        const int rr   = gr & 255;
        #pragma unroll
        for (int nd = 0; nd < 12; ++nd) {
            const int gc = h * HD + nd * 16 + l15;
            const int t  = gc >> 6;
            const int cc = gc & 63;
            Ximg[((size_t)(mt * 12 + t) * 256 + rr) * 64 + (cc ^ ((rr & 7) << 3))] =
                (_Float16)(Oacc[nd][j] * inv);
        }
    }
}

// ---------------------------------------------------------------------------
extern "C" void kernel_launch(void* const* d_in, const int* in_sizes, int n_in,
                              void* d_out, int out_size, void* d_ws, size_t ws_size,
                              hipStream_t stream)
{
    const float* q  = (const float*)d_in[0];
    const float* k  = (const float*)d_in[1];
    const float* v  = (const float*)d_in[2];
    const float* Wq = (const float*)d_in[3];
    const float* Wk = (const float*)d_in[4];
    const float* Wv = (const float*)d_in[5];
    const float* Wp = (const float*)d_in[6];
    const float* bp = (const float*)d_in[7];

    const size_t HSZ  = (size_t)NBATCH * NH * SEQ * HD;  // 12,582,912
    const size_t WIMG = 4 * 12 * 12288;                  // 589,824 halves
    _Float16* Qh    = (_Float16*)d_ws;
    _Float16* KVimg = Qh + HSZ;          // 2*HSZ halves
    _Float16* Ximg  = KVimg + 2 * HSZ;
    _Float16* Wpimg = Ximg + HSZ;        // ~101.8 MB total ws
    _Float16* Wqimg = (_Float16*)d_out;  // 3 contiguous images in d_out scratch
    _Float16* Wkimg = Wqimg + WIMG;
    _Float16* Wvimg = Wkimg + WIMG;

    cvt_w<<<dim3(576, 4), dim3(256), 0, stream>>>(Wq, Wk, Wv, Wp,
                                                  Wqimg, Wkimg, Wvimg, Wpimg);
    dim3 g2(128, 4), b2(512);
    gemm_p2<0><<<g2, b2, 0, stream>>>(q, Wqimg, Qh, SCALE_F * LOG2E);
    gemm_p2<1><<<g2, b2, 0, stream>>>(k, Wkimg, KVimg, 1.0f);
    gemm_p2<3><<<g2, b2, 0, stream>>>(v, Wvimg, KVimg, 1.0f);
    attn7<<<dim3(512), dim3(512), 0, stream>>>(Qh, KVimg, Ximg);
    gemm_x2<<<g2, b2, 0, stream>>>(Ximg, Wpimg, (float*)d_out, bp);
}

// Round 15
// 247.301 us; speedup vs baseline: 1.0736x; 1.0068x over previous
//
#include <hip/hip_runtime.h>
#include <hip/hip_fp16.h>

#define DIMC 768
#define NH 4
#define HD 192
#define SEQ 2048
#define NBATCH 8
#define SCALE_F 0.07216878364870323f  /* 192^-0.5 */
#define LOG2E   1.4426950408889634f
#define DEFER_THR 8.0f                /* log2-domain defer-max threshold */

typedef _Float16 f16x8 __attribute__((ext_vector_type(8)));
typedef _Float16 f16x4 __attribute__((ext_vector_type(4)));
typedef float    f32x4 __attribute__((ext_vector_type(4)));

__device__ __forceinline__ f32x4 mfma16(f16x8 a, f16x8 b, f32x4 c) {
    return __builtin_amdgcn_mfma_f32_16x16x32_f16(a, b, c, 0, 0, 0);
}
__device__ __forceinline__ void gl16(const void* g, void* l) {
    __builtin_amdgcn_global_load_lds(
        (const __attribute__((address_space(1))) unsigned int*)g,
        (__attribute__((address_space(3))) unsigned int*)l, 16, 0, 0);
}
__device__ __forceinline__ float exp2_hw(float x) {
    return __builtin_amdgcn_exp2f(x);
}

// ---------------------------------------------------------------------------
// cvt_w: fp32 W[768][768] -> fp16 pre-swizzled 192-row tile images.
// idx = ((nt*12 + t)*192 + rr)*64 + (cc ^ ((rr&7)<<3)).   (verbatim r11)
// ---------------------------------------------------------------------------
__global__ __launch_bounds__(256)
void cvt_w(const float* __restrict__ w0, const float* __restrict__ w1,
           const float* __restrict__ w2, const float* __restrict__ w3,
           _Float16* __restrict__ o0, _Float16* __restrict__ o1,
           _Float16* __restrict__ o2, _Float16* __restrict__ o3)
{
    const float* src = (blockIdx.y == 0) ? w0 : (blockIdx.y == 1) ? w1
                     : (blockIdx.y == 2) ? w2 : w3;
    _Float16* dst = (blockIdx.y == 0) ? o0 : (blockIdx.y == 1) ? o1
                  : (blockIdx.y == 2) ? o2 : o3;
    const int e   = blockIdx.x * 256 + threadIdx.x;
    const int row = e / 192;
    const int col = (e - row * 192) * 4;
    const float4 v = *(const float4*)(src + (size_t)row * DIMC + col);
    const int nt = row / 192, rr = row - nt * 192;
    const int t  = col >> 6,  cc = col & 63;
    f16x4 h = {(_Float16)v.x, (_Float16)v.y, (_Float16)v.z, (_Float16)v.w};
    *(f16x4*)(dst + ((size_t)(nt * 12 + t) * 192 + rr) * 64 + (cc ^ ((rr & 7) << 3))) = h;
}

// ---------------------------------------------------------------------------
// 8-phase 256x192 GEMM helpers: 8 waves (2M x 4N), wave tile 128x48 (NF=3).
// (verbatim r11)
// ---------------------------------------------------------------------------
__device__ __forceinline__ void phase_reads(const _Float16* As, const _Float16* Bs,
                                            int wr, int wc, int l15, int l4, int q,
                                            f16x8 af[2][2], f16x8 bf[2][3], bool loadB)
{
    #pragma unroll
    for (int ks = 0; ks < 2; ++ks) {
        const int cb = ks * 32 + l4 * 8;
        #pragma unroll
        for (int mm = 0; mm < 2; ++mm) {
            const int row = wr * 128 + (q * 2 + mm) * 16 + l15;
            af[ks][mm] = *(const f16x8*)(As + (size_t)row * 64 + (cb ^ ((row & 7) << 3)));
        }
        if (loadB) {
            #pragma unroll
            for (int n = 0; n < 3; ++n) {
                const int row = wc * 48 + n * 16 + l15;
                bf[ks][n] = *(const f16x8*)(Bs + (size_t)row * 64 + (cb ^ ((row & 7) << 3)));
            }
        }
    }
}
__device__ __forceinline__ void phase_mfma(int q, f16x8 af[2][2], f16x8 bf[2][3],
                                           f32x4 acc[8][3])
{
    __builtin_amdgcn_s_barrier();
    asm volatile("s_waitcnt lgkmcnt(0)" ::: "memory");
    __builtin_amdgcn_s_setprio(1);
    #pragma unroll
    for (int ks = 0; ks < 2; ++ks)
        #pragma unroll
        for (int mm = 0; mm < 2; ++mm)
            #pragma unroll
            for (int n = 0; n < 3; ++n)
                acc[q * 2 + mm][n] = mfma16(af[ks][mm], bf[ks][n], acc[q * 2 + mm][n]);
    __builtin_amdgcn_s_setprio(0);
}

// ---------------------------------------------------------------------------
// Projection GEMM (8-phase, 256x192, grid 64x4 = 256 = 1/CU). Verbatim r11.
// ---------------------------------------------------------------------------
template<int MODE>
__global__ __launch_bounds__(512, 2)
void gemm_p8(const float* __restrict__ A, const _Float16* __restrict__ Wimg,
             _Float16* __restrict__ Y, float scale)
{
    __shared__ __attribute__((aligned(16))) _Float16 Abuf[2][16384];
    __shared__ __attribute__((aligned(16))) _Float16 Bbuf[2][12288];

    const int tid  = threadIdx.x;
    const int wid  = tid >> 6;
    const int lane = tid & 63;
    const int l15  = lane & 15;
    const int l4   = lane >> 4;
    const int wr   = wid >> 2;
    const int wc   = wid & 3;
    const int m0   = blockIdx.x * 256;
    const int nt   = blockIdx.y;

    const unsigned char* Wt = (const unsigned char*)(Wimg + (size_t)nt * 12 * 12288);

    f32x4 acc[8][3];
    #pragma unroll
    for (int m = 0; m < 8; ++m)
        #pragma unroll
        for (int n = 0; n < 3; ++n)
            acc[m][n] = (f32x4){0.f, 0.f, 0.f, 0.f};

    float4 rA[8];
    auto loadA = [&](int t) {
        #pragma unroll
        for (int p = 0; p < 8; ++p) {
            const int linear = p * 512 + tid;
            const int row = linear >> 4, qc = (linear & 15) * 4;
            rA[p] = *(const float4*)(A + (size_t)(m0 + row) * DIMC + t * 64 + qc);
        }
    };
    auto writeA = [&](int buf) {
        #pragma unroll
        for (int p = 0; p < 8; ++p) {
            const int linear = p * 512 + tid;
            const int row = linear >> 4, qc = (linear & 15) * 4;
            f16x4 h = {(_Float16)rA[p].x, (_Float16)rA[p].y,
                       (_Float16)rA[p].z, (_Float16)rA[p].w};
            *(f16x4*)(&Abuf[buf][row * 64 + (qc ^ ((row & 7) << 3))]) = h;
        }
    };
    auto stageB = [&](int t) {
        const unsigned char* src = Wt + (size_t)t * 24576;
        #pragma unroll
        for (int u = 0; u < 3; ++u)
            gl16(src + u * 8192 + tid * 16, &Bbuf[t & 1][u * 4096 + tid * 8]);
    };

    loadA(0);
    stageB(0);
    asm volatile("s_waitcnt vmcnt(3)" ::: "memory");
    writeA(0);
    loadA(1);
    asm volatile("s_waitcnt vmcnt(8)" ::: "memory");
    asm volatile("s_waitcnt lgkmcnt(0)" ::: "memory");
    __builtin_amdgcn_s_barrier();

    for (int t = 0; t < 12; ++t) {
        const _Float16* As = &Abuf[t & 1][0];
        const _Float16* Bs = &Bbuf[t & 1][0];
        f16x8 af[2][2], bf[2][3];

        phase_reads(As, Bs, wr, wc, l15, l4, 0, af, bf, true);
        if (t < 11) stageB(t + 1);
        phase_mfma(0, af, bf, acc);
        __builtin_amdgcn_s_barrier();

        phase_reads(As, Bs, wr, wc, l15, l4, 1, af, bf, false);
        phase_mfma(1, af, bf, acc);
        __builtin_amdgcn_s_barrier();

        phase_reads(As, Bs, wr, wc, l15, l4, 2, af, bf, false);
        if (t < 11) {
            asm volatile("s_waitcnt vmcnt(3)" ::: "memory");
            writeA((t + 1) & 1);
            if (t < 10) loadA(t + 2);
        }
        phase_mfma(2, af, bf, acc);
        __builtin_amdgcn_s_barrier();

        phase_reads(As, Bs, wr, wc, l15, l4, 3, af, bf, false);
        phase_mfma(3, af, bf, acc);
        if (t < 10)       asm volatile("s_waitcnt vmcnt(8)" ::: "memory");
        else if (t == 10) asm volatile("s_waitcnt vmcnt(0)" ::: "memory");
        __builtin_amdgcn_s_barrier();
    }

    #pragma unroll
    for (int m = 0; m < 8; ++m) {
        const int rbase = m0 + wr * 128 + m * 16 + l4 * 4;
        #pragma unroll
        for (int n = 0; n < 3; ++n) {
            const int d = wc * 48 + n * 16 + l15;
            #pragma unroll
            for (int j = 0; j < 4; ++j) {
                const int r  = rbase + j;
                const int b  = r >> 11;
                const int nn = r & (SEQ - 1);
                if (MODE == 0) {
                    Y[((size_t)(b * NH + nt) * SEQ + nn) * HD + d] =
                        (_Float16)(acc[m][n][j] * scale);
                } else {
                    const int kt  = nn >> 5;
                    const int key = nn & 31;
                    const size_t tb = ((size_t)(b * NH + nt) * 64 + kt) * 12288;
                    size_t idx;
                    if (MODE == 1)
                        idx = tb + (size_t)key * HD + (d ^ ((key & 7) << 3));
                    else
                        idx = tb + 6144 + (((size_t)(key >> 3) * 192 + d) << 3) + (key & 7);
                    Y[idx] = (_Float16)acc[m][n][j];
                }
            }
        }
    }
}

// ---------------------------------------------------------------------------
// Final GEMM (8-phase, 256x192, grid 64x4). Verbatim r11.
// ---------------------------------------------------------------------------
__global__ __launch_bounds__(512, 2)
void gemm_x8(const _Float16* __restrict__ Ximg, const _Float16* __restrict__ Wimg,
             float* __restrict__ out, const float* __restrict__ bias)
{
    __shared__ __attribute__((aligned(16))) _Float16 Abuf[2][16384];
    __shared__ __attribute__((aligned(16))) _Float16 Bbuf[2][12288];

    const int tid  = threadIdx.x;
    const int wid  = tid >> 6;
    const int lane = tid & 63;
    const int l15  = lane & 15;
    const int l4   = lane >> 4;
    const int wr   = wid >> 2;
    const int wc   = wid & 3;
    const int mt   = blockIdx.x;
    const int nt   = blockIdx.y;

    const unsigned char* Xt = (const unsigned char*)(Ximg + (size_t)mt * 12 * 16384);
    const unsigned char* Wt = (const unsigned char*)(Wimg + (size_t)nt * 12 * 12288);

    f32x4 acc[8][3];
    #pragma unroll
    for (int m = 0; m < 8; ++m)
        #pragma unroll
        for (int n = 0; n < 3; ++n)
            acc[m][n] = (f32x4){0.f, 0.f, 0.f, 0.f};

    auto stageAB = [&](int t) {
        const unsigned char* sa = Xt + (size_t)t * 32768;
        const unsigned char* sb = Wt + (size_t)t * 24576;
        #pragma unroll
        for (int u = 0; u < 4; ++u)
            gl16(sa + u * 8192 + tid * 16, &Abuf[t & 1][u * 4096 + tid * 8]);
        #pragma unroll
        for (int u = 0; u < 3; ++u)
            gl16(sb + u * 8192 + tid * 16, &Bbuf[t & 1][u * 4096 + tid * 8]);
    };

    stageAB(0);
    asm volatile("s_waitcnt vmcnt(0)" ::: "memory");
    __builtin_amdgcn_s_barrier();

    for (int t = 0; t < 12; ++t) {
        const _Float16* As = &Abuf[t & 1][0];
        const _Float16* Bs = &Bbuf[t & 1][0];
        f16x8 af[2][2], bf[2][3];

        phase_reads(As, Bs, wr, wc, l15, l4, 0, af, bf, true);
        if (t < 11) stageAB(t + 1);
        phase_mfma(0, af, bf, acc);
        __builtin_amdgcn_s_barrier();

        phase_reads(As, Bs, wr, wc, l15, l4, 1, af, bf, false);
        phase_mfma(1, af, bf, acc);
        __builtin_amdgcn_s_barrier();

        phase_reads(As, Bs, wr, wc, l15, l4, 2, af, bf, false);
        phase_mfma(2, af, bf, acc);
        __builtin_amdgcn_s_barrier();

        phase_reads(As, Bs, wr, wc, l15, l4, 3, af, bf, false);
        phase_mfma(3, af, bf, acc);
        if (t < 11) asm volatile("s_waitcnt vmcnt(0)" ::: "memory");
        __builtin_amdgcn_s_barrier();
    }

    #pragma unroll
    for (int m = 0; m < 8; ++m) {
        const int rbase = mt * 256 + wr * 128 + m * 16 + l4 * 4;
        #pragma unroll
        for (int n = 0; n < 3; ++n) {
            const int c = nt * 192 + wc * 48 + n * 16 + l15;
            const float bv = bias[c];
            #pragma unroll
            for (int j = 0; j < 4; ++j)
                out[(size_t)(rbase + j) * DIMC + c] = acc[m][n][j] + bv;
        }
    }
}

// ---------------------------------------------------------------------------
// Flash attention v10: 2 m-frags per wave (32 q-rows) -> each K/V fragment
// read feeds 2 MFMAs, halving LDS-read bytes per MFMA (attn7 was LDS-BW
// bound: 26KB/24 MFMA/wave/tile ~= 133us model vs 126.5 measured).
// 256 thr = 4 waves x 32 q-rows, KVBLK=32, 58KB LDS, 2 blocks/CU
// (launch_bounds(256,2): VGPR<=256, no spill), gl16 dbuf KV vmcnt(6),
// defer-max softmax, per-lane lrow, chunked V. Structure otherwise attn7.
// ---------------------------------------------------------------------------
__global__ __launch_bounds__(256, 2)
void attn10(const _Float16* __restrict__ Qh, const _Float16* __restrict__ KVimg,
            _Float16* __restrict__ Ximg)
{
    __shared__ __attribute__((aligned(16))) _Float16 KV[2][12288]; // K:0..6144, V:6144..
    __shared__ __attribute__((aligned(16))) _Float16 Ps[4][32][40];

    const int tid  = threadIdx.x;
    const int wid  = tid >> 6;
    const int lane = tid & 63;
    const int l15  = lane & 15;
    const int l4   = lane >> 4;

    const int bid   = blockIdx.x;
    const int local = bid >> 3;
    const int bh    = (bid & 7) * 4 + (local >> 4);
    const int qt    = local & 15;

    const unsigned char* KVt = (const unsigned char*)KVimg + (size_t)bh * 64 * 24576;

    // stage one 24KB KV tile: 256 thr x 6 gl16
    #pragma unroll
    for (int s = 0; s < 6; ++s)
        gl16(KVt + (size_t)(s * 256 + tid) * 16, &KV[0][(size_t)(s * 256 + tid) * 8]);

    const int q0 = qt * 128 + wid * 32;
    const size_t qbase = (size_t)bh * SEQ * HD;
    f16x8 qf[2][6];
    #pragma unroll
    for (int mm = 0; mm < 2; ++mm)
        #pragma unroll
        for (int kk = 0; kk < 6; ++kk)
            qf[mm][kk] = *(const f16x8*)(Qh + qbase +
                         (size_t)(q0 + mm * 16 + l15) * HD + kk * 32 + l4 * 8);

    f32x4 Oacc[2][12];
    #pragma unroll
    for (int mm = 0; mm < 2; ++mm)
        #pragma unroll
        for (int nd = 0; nd < 12; ++nd)
            Oacc[mm][nd] = (f32x4){0.f, 0.f, 0.f, 0.f};
    float mrow[2][4], lrow[2][4];
    #pragma unroll
    for (int mm = 0; mm < 2; ++mm)
        #pragma unroll
        for (int j = 0; j < 4; ++j) { mrow[mm][j] = -1e30f; lrow[mm][j] = 0.f; }

    for (int kt = 0; kt < SEQ / 32; ++kt) {
        const int cur = kt & 1;
        if (kt < SEQ / 32 - 1) {
            const unsigned char* KVn = KVt + (size_t)(kt + 1) * 24576;
            #pragma unroll
            for (int s = 0; s < 6; ++s)
                gl16(KVn + (size_t)(s * 256 + tid) * 16,
                     &KV[cur ^ 1][(size_t)(s * 256 + tid) * 8]);
            asm volatile("s_waitcnt vmcnt(6)" ::: "memory");
        } else {
            asm volatile("s_waitcnt vmcnt(0)" ::: "memory");
        }
        __builtin_amdgcn_s_barrier();
        __builtin_amdgcn_sched_barrier(0);

        const _Float16* Kc = &KV[cur][0];
        const _Float16* Vc = &KV[cur][6144];

        // ---- S = Q K^T: K frag read once, used by both m-frags ----
        f32x4 sacc[2][2];
        #pragma unroll
        for (int mm = 0; mm < 2; ++mm)
            #pragma unroll
            for (int nn = 0; nn < 2; ++nn)
                sacc[mm][nn] = (f32x4){0.f, 0.f, 0.f, 0.f};
        __builtin_amdgcn_s_setprio(1);
        #pragma unroll
        for (int kk = 0; kk < 6; ++kk) {
            const int cb = (kk * 32 + l4 * 8) ^ ((l15 & 7) << 3);
            #pragma unroll
            for (int nn = 0; nn < 2; ++nn) {
                const f16x8 kf = *(const f16x8*)(Kc + (size_t)(nn * 16 + l15) * HD + cb);
                sacc[0][nn] = mfma16(qf[0][kk], kf, sacc[0][nn]);
                sacc[1][nn] = mfma16(qf[1][kk], kf, sacc[1][nn]);
            }
        }
        __builtin_amdgcn_s_setprio(0);

        // ---- defer-max online softmax ----
        float lm[2][4];
        bool need = false;
        #pragma unroll
        for (int mm = 0; mm < 2; ++mm)
            #pragma unroll
            for (int j = 0; j < 4; ++j) {
                lm[mm][j] = fmaxf(sacc[mm][0][j], sacc[mm][1][j]);
                need |= (lm[mm][j] > mrow[mm][j] + DEFER_THR);
            }
        if (__any(need)) {
            #pragma unroll
            for (int mm = 0; mm < 2; ++mm)
                #pragma unroll
                for (int j = 0; j < 4; ++j) {
                    float v = lm[mm][j];
                    v = fmaxf(v, __shfl_xor(v, 1));
                    v = fmaxf(v, __shfl_xor(v, 2));
                    v = fmaxf(v, __shfl_xor(v, 4));
                    v = fmaxf(v, __shfl_xor(v, 8));
                    const float mnew = fmaxf(mrow[mm][j], v);
                    const float f    = exp2_hw(mrow[mm][j] - mnew);
                    mrow[mm][j] = mnew;
                    lrow[mm][j] *= f;
                    #pragma unroll
                    for (int nd = 0; nd < 12; ++nd)
                        Oacc[mm][nd][j] *= f;
                }
        }
        #pragma unroll
        for (int mm = 0; mm < 2; ++mm)
            #pragma unroll
            for (int j = 0; j < 4; ++j) {
                const float p0 = exp2_hw(sacc[mm][0][j] - mrow[mm][j]);
                const float p1 = exp2_hw(sacc[mm][1][j] - mrow[mm][j]);
                sacc[mm][0][j] = p0;
                sacc[mm][1][j] = p1;
                lrow[mm][j] += p0 + p1;
            }

        // ---- P -> per-wave LDS -> A-frags ----
        #pragma unroll
        for (int mm = 0; mm < 2; ++mm)
            #pragma unroll
            for (int nn = 0; nn < 2; ++nn)
                #pragma unroll
                for (int j = 0; j < 4; ++j)
                    Ps[wid][mm * 16 + l4 * 4 + j][nn * 16 + l15] =
                        (_Float16)sacc[mm][nn][j];
        asm volatile("s_waitcnt lgkmcnt(0)" ::: "memory");
        __builtin_amdgcn_sched_barrier(0);

        // ---- O += P V: V frag read once, used by both m-frags ----
        f16x8 pf[2];
        #pragma unroll
        for (int mm = 0; mm < 2; ++mm)
            pf[mm] = *(const f16x8*)(&Ps[wid][mm * 16 + l15][l4 * 8]);
        __builtin_amdgcn_s_setprio(1);
        #pragma unroll
        for (int nd = 0; nd < 12; ++nd) {
            const f16x8 vfr = *(const f16x8*)(Vc + (((size_t)l4 * 192 + nd * 16 + l15) << 3));
            Oacc[0][nd] = mfma16(pf[0], vfr, Oacc[0][nd]);
            Oacc[1][nd] = mfma16(pf[1], vfr, Oacc[1][nd]);
        }
        __builtin_amdgcn_s_setprio(0);

        __builtin_amdgcn_s_barrier();
        __builtin_amdgcn_sched_barrier(0);
    }

    // epilogue: reduce lrow across 16-lane key group, write 256-row X image
    #pragma unroll
    for (int mm = 0; mm < 2; ++mm)
        #pragma unroll
        for (int j = 0; j < 4; ++j) {
            float s = lrow[mm][j];
            s += __shfl_xor(s, 1);
            s += __shfl_xor(s, 2);
            s += __shfl_xor(s, 4);
            s += __shfl_xor(s, 8);
            lrow[mm][j] = s;
        }
    const int b = bh >> 2;
    const int h = bh & 3;
    #pragma unroll
    for (int mm = 0; mm < 2; ++mm)
        #pragma unroll
        for (int j = 0; j < 4; ++j) {
            const float inv = 1.f / lrow[mm][j];
            const int qrow = q0 + mm * 16 + l4 * 4 + j;
            const int gr   = b * SEQ + qrow;
            const int mt   = gr >> 8;
            const int rr   = gr & 255;
            #pragma unroll
            for (int nd = 0; nd < 12; ++nd) {
                const int gc = h * HD + nd * 16 + l15;
                const int t  = gc >> 6;
                const int cc = gc & 63;
                Ximg[((size_t)(mt * 12 + t) * 256 + rr) * 64 + (cc ^ ((rr & 7) << 3))] =
                    (_Float16)(Oacc[mm][nd][j] * inv);
            }
        }
}

// ---------------------------------------------------------------------------
extern "C" void kernel_launch(void* const* d_in, const int* in_sizes, int n_in,
                              void* d_out, int out_size, void* d_ws, size_t ws_size,
                              hipStream_t stream)
{
    const float* q  = (const float*)d_in[0];
    const float* k  = (const float*)d_in[1];
    const float* v  = (const float*)d_in[2];
    const float* Wq = (const float*)d_in[3];
    const float* Wk = (const float*)d_in[4];
    const float* Wv = (const float*)d_in[5];
    const float* Wp = (const float*)d_in[6];
    const float* bp = (const float*)d_in[7];

    const size_t HSZ  = (size_t)NBATCH * NH * SEQ * HD;  // 12,582,912
    const size_t WIMG = 4 * 12 * 12288;                  // 589,824 halves
    _Float16* Qh    = (_Float16*)d_ws;
    _Float16* KVimg = Qh + HSZ;          // 2*HSZ halves
    _Float16* Ximg  = KVimg + 2 * HSZ;
    _Float16* Wpimg = Ximg + HSZ;        // ~101.8 MB total ws
    _Float16* Wqimg = (_Float16*)d_out;  // 3 contiguous images in d_out scratch
    _Float16* Wkimg = Wqimg + WIMG;
    _Float16* Wvimg = Wkimg + WIMG;

    cvt_w<<<dim3(576, 4), dim3(256), 0, stream>>>(Wq, Wk, Wv, Wp,
                                                  Wqimg, Wkimg, Wvimg, Wpimg);
    dim3 g8(64, 4), b8(512);
    gemm_p8<0><<<g8, b8, 0, stream>>>(q, Wqimg, Qh, SCALE_F * LOG2E);
    gemm_p8<1><<<g8, b8, 0, stream>>>(k, Wkimg, KVimg, 1.0f);
    gemm_p8<3><<<g8, b8, 0, stream>>>(v, Wvimg, KVimg, 1.0f);
    attn10<<<dim3(512), dim3(256), 0, stream>>>(Qh, KVimg, Ximg);
    gemm_x8<<<g8, b8, 0, stream>>>(Ximg, Wpimg, (float*)d_out, bp);
}